// Round 1
// baseline (94.508 us; speedup 1.0000x reference)
//
#include <hip/hip_runtime.h>
#include <math.h>

// HOG: x (N,3,224,224) f32 -> out (N, 9*28*28) f32
// gx = sobelX(sum_c x), gy = sobelY(sum_c x)   [conv = cross-correlation, SAME zero pad]
// mag = sqrt(gx^2+gy^2); ang = |atan2(gx,gy)|; bin = floor(ang/pi*8) in [0,8]
// out[n,bin,cr,cw] = sum over 8x8 cell of mag where pixel bin matches.

namespace {
constexpr int Himg = 224;
constexpr int Wimg = 224;
constexpr int NCELL = 28;   // 224/8
constexpr int BINS  = 9;
constexpr int ROWS  = 10;   // 8 cell rows + 1 halo above + 1 below
constexpr int LDSW  = 232;  // 4 left pad + 224 + 4 right pad (keeps float4 LDS stores 16B aligned)

__global__ __launch_bounds__(256) void hog_kernel(const float* __restrict__ x,
                                                  float* __restrict__ out) {
    const int n  = blockIdx.y;   // sample
    const int cr = blockIdx.x;   // cell row 0..27
    const int t  = threadIdx.x;  // 0..255

    __shared__ float s[ROWS][LDSW];        // channel-sum tile, col index = w + 4
    __shared__ float hist[NCELL * BINS];   // per-cell 9-bin histograms

    // zero histogram
    if (t < NCELL * BINS) hist[t] = 0.0f;
    // zero the left/right pads (covers w=-1 and w=224 halo columns)
    if (t < ROWS * 8) {
        int r = t >> 3;
        int c = t & 7;
        int col = (c < 4) ? c : (224 + c);  // cols 0..3 and 228..231
        s[r][col] = 0.0f;
    }

    const int h0 = cr * 8 - 1;                       // image row of LDS row 0
    const float* xb = x + (size_t)n * 3 * Himg * Wimg;

    // Stage: 10 rows x 56 float4 chunks, summed over 3 channels.
    for (int idx = t; idx < ROWS * 56; idx += 256) {
        int r = idx / 56;
        int q = idx - r * 56;
        int w = q * 4;
        int h = h0 + r;
        float4 v = make_float4(0.f, 0.f, 0.f, 0.f);
        if (h >= 0 && h < Himg) {
            const float* r0 = xb + (size_t)h * Wimg;            // channel 0
            const float* r1 = r0 + Himg * Wimg;                 // channel 1
            const float* r2 = r1 + Himg * Wimg;                 // channel 2
            float4 a = *(const float4*)(r0 + w);
            float4 b = *(const float4*)(r1 + w);
            float4 c4 = *(const float4*)(r2 + w);
            v.x = a.x + b.x + c4.x;
            v.y = a.y + b.y + c4.y;
            v.z = a.z + b.z + c4.z;
            v.w = a.w + b.w + c4.w;
        }
        *(float4*)&s[r][4 + w] = v;   // 16B-aligned (4-float left pad, 232-float stride)
    }
    __syncthreads();

    // Compute: 8 rows x 224 cols. Thread layout: row = t/32, 7 cols strided by 32.
    const int row  = t >> 5;   // 0..7
    const int col0 = t & 31;
    const float PI_F = 3.14159265358979323846f;  // rounds to float(math.pi)

#pragma unroll
    for (int k = 0; k < 7; ++k) {
        int w = col0 + 32 * k;
        const float* sr0 = &s[row][4 + w];       // image row h-1
        const float* sr1 = &s[row + 1][4 + w];   // image row h
        const float* sr2 = &s[row + 2][4 + w];   // image row h+1
        float gx = (sr0[1] - sr0[-1]) + 2.0f * (sr1[1] - sr1[-1]) + (sr2[1] - sr2[-1]);
        float gy = (sr2[-1] + 2.0f * sr2[0] + sr2[1]) - (sr0[-1] + 2.0f * sr0[0] + sr0[1]);
        float mag = sqrtf(gx * gx + gy * gy);
        float ang = fabsf(atan2f(gx, gy));       // |atan2(y=gx, x=gy)| in [0, pi]
        int bin = (int)(ang / PI_F * 8.0f);      // same op order as reference
        bin = bin > 8 ? 8 : bin;                 // ang==pi lands exactly on 8
        atomicAdd(&hist[(w >> 3) * BINS + bin], mag);
    }
    __syncthreads();

    // Write 252 outputs: out[n, bin, cr, cw], coalesced along cw.
    if (t < NCELL * BINS) {
        int bin = t / NCELL;
        int cw  = t - bin * NCELL;
        out[((size_t)n * BINS + bin) * (NCELL * NCELL) + (size_t)cr * NCELL + cw] =
            hist[cw * BINS + bin];
    }
}
}  // namespace

extern "C" void kernel_launch(void* const* d_in, const int* in_sizes, int n_in,
                              void* d_out, int out_size, void* d_ws, size_t ws_size,
                              hipStream_t stream) {
    const float* x = (const float*)d_in[0];
    float* out = (float*)d_out;
    const int N = in_sizes[0] / (3 * Himg * Wimg);
    dim3 grid(NCELL, N);
    hog_kernel<<<grid, 256, 0, stream>>>(x, out);
}

// Round 2
// 94.073 us; speedup vs baseline: 1.0046x; 1.0046x over previous
//
#include <hip/hip_runtime.h>
#include <math.h>

// HOG: x (N,3,224,224) f32 -> out (N, 9*28*28) f32
// gx = sobelX(sum_c x), gy = sobelY(sum_c x)   [SAME zero pad]
// mag = sqrt(gx^2+gy^2); ang = |atan2(gx,gy)|; bin = floor(ang/pi*8) in [0,8]
// Bin via comparison network: ang >= k*pi/8  <=>  gy <= mag*cos(k*pi/8)
// (cos monotone decreasing on [0,pi]; gy = mag*cos(ang)). Guarded fallback to
// the exact reference float pipeline within 1e-4*mag of any boundary keeps
// bit-identical binning (guard band ~1e-4 rad >> ~6e-7 rad ref rounding fuzz).

namespace {
constexpr int Himg = 224;
constexpr int Wimg = 224;
constexpr int NCELL = 28;   // 224/8
constexpr int BINS  = 9;
constexpr int ROWS  = 10;   // 8 cell rows + halo above/below
constexpr int LDSW  = 232;  // 4 left pad + 224 + 4 right pad (16B-aligned stores)

__global__ __launch_bounds__(256) void hog_kernel(const float* __restrict__ x,
                                                  float* __restrict__ out) {
    const int n  = blockIdx.y;   // sample
    const int cr = blockIdx.x;   // cell row 0..27
    const int t  = threadIdx.x;  // 0..255

    __shared__ float s[ROWS][LDSW];        // channel-sum tile, col index = w + 4
    __shared__ float hist[NCELL * BINS];   // per-cell 9-bin histograms

    if (t < NCELL * BINS) hist[t] = 0.0f;
    if (t < ROWS * 8) {                    // zero left/right halo pads
        int r = t >> 3;
        int c = t & 7;
        int col = (c < 4) ? c : (224 + c);
        s[r][col] = 0.0f;
    }

    const int h0 = cr * 8 - 1;
    const float* xb = x + (size_t)n * 3 * Himg * Wimg;

    // Stage: 10 rows x 56 float4 chunks, summed over 3 channels.
    for (int idx = t; idx < ROWS * 56; idx += 256) {
        int r = idx / 56;
        int q = idx - r * 56;
        int w = q * 4;
        int h = h0 + r;
        float4 v = make_float4(0.f, 0.f, 0.f, 0.f);
        if (h >= 0 && h < Himg) {
            const float* r0 = xb + (size_t)h * Wimg;
            const float* r1 = r0 + Himg * Wimg;
            const float* r2 = r1 + Himg * Wimg;
            float4 a = *(const float4*)(r0 + w);
            float4 b = *(const float4*)(r1 + w);
            float4 c4 = *(const float4*)(r2 + w);
            v.x = a.x + b.x + c4.x;
            v.y = a.y + b.y + c4.y;
            v.z = a.z + b.z + c4.z;
            v.w = a.w + b.w + c4.w;
        }
        *(float4*)&s[r][4 + w] = v;
    }
    __syncthreads();

    const int row  = t >> 5;   // 0..7
    const int col0 = t & 31;
    const float PI_F = 3.14159265358979323846f;
    const float CK[8] = {0.92387953f, 0.70710678f, 0.38268343f, 0.0f,
                         -0.38268343f, -0.70710678f, -0.92387953f, -1.0f};

#pragma unroll
    for (int k = 0; k < 7; ++k) {
        int w = col0 + 32 * k;
        const float* sr0 = &s[row][4 + w];
        const float* sr1 = &s[row + 1][4 + w];
        const float* sr2 = &s[row + 2][4 + w];
        float gx = (sr0[1] - sr0[-1]) + 2.0f * (sr1[1] - sr1[-1]) + (sr2[1] - sr2[-1]);
        float gy = (sr2[-1] + 2.0f * sr2[0] + sr2[1]) - (sr0[-1] + 2.0f * sr0[0] + sr0[1]);
        float mag = sqrtf(gx * gx + gy * gy);

        // bin = #{ j : gy <= mag*cos(j*pi/8) }  (= floor(|atan2(gx,gy)|/pi*8))
        float negy = -gy;
        int bin = 0;
        float guard = 1e30f;
#pragma unroll
        for (int j = 0; j < 8; ++j) {
            float sj = fmaf(mag, CK[j], negy);   // mag*c_j - gy
            bin += (sj >= 0.0f) ? 1 : 0;
            guard = fminf(guard, fabsf(sj));
        }
        if (guard < mag * 1e-4f) {
            // near a bin boundary: replicate the reference float pipeline exactly
            float ang = fabsf(atan2f(gx, gy));
            bin = (int)(ang / PI_F * 8.0f);
            bin = bin > 8 ? 8 : bin;
        }
        atomicAdd(&hist[(w >> 3) * BINS + bin], mag);
    }
    __syncthreads();

    // Write 252 outputs: out[n, bin, cr, cw], coalesced along cw.
    if (t < NCELL * BINS) {
        int bin = t / NCELL;
        int cw  = t - bin * NCELL;
        out[((size_t)n * BINS + bin) * (NCELL * NCELL) + (size_t)cr * NCELL + cw] =
            hist[cw * BINS + bin];
    }
}
}  // namespace

extern "C" void kernel_launch(void* const* d_in, const int* in_sizes, int n_in,
                              void* d_out, int out_size, void* d_ws, size_t ws_size,
                              hipStream_t stream) {
    const float* x = (const float*)d_in[0];
    float* out = (float*)d_out;
    const int N = in_sizes[0] / (3 * Himg * Wimg);
    dim3 grid(NCELL, N);
    hog_kernel<<<grid, 256, 0, stream>>>(x, out);
}

// Round 3
// 83.834 us; speedup vs baseline: 1.1273x; 1.1221x over previous
//
#include <hip/hip_runtime.h>
#include <math.h>

// HOG: x (N,3,224,224) f32 -> out (N, 9*28*28) f32
// gx = sobelX(sum_c x), gy = sobelY(sum_c x)   [SAME zero pad]
// mag = sqrt(gx^2+gy^2); bin = floor(|atan2(gx,gy)|/pi*8) in [0,8]
// Bin via comparison network (gy <= mag*cos(k*pi/8)), guarded atan2f fallback
// within 1e-4*mag of any boundary -> binning provably matches the reference.
// R3 structure: thread = image column (stride-1 LDS reads, conflict-free),
// 3x3 register sliding window down the 8 rows, per-thread 9-bin register
// accumulators (no LDS atomics), one-time LDS reduction across the 8 columns
// of each cell.

namespace {
constexpr int Himg = 224;
constexpr int Wimg = 224;
constexpr int NCELL = 28;   // 224/8
constexpr int BINS  = 9;
constexpr int ROWS  = 10;   // 8 cell rows + halo above/below
constexpr int LDSW  = 232;  // 4 left pad + 224 + 4 right pad (16B-aligned stores)

__global__ __launch_bounds__(256) void hog_kernel(const float* __restrict__ x,
                                                  float* __restrict__ out) {
    const int n  = blockIdx.y;   // sample
    const int cr = blockIdx.x;   // cell row 0..27
    const int t  = threadIdx.x;  // 0..255

    __shared__ float s[ROWS][LDSW];        // channel-sum tile, col index = w + 4
    __shared__ float h2[Wimg * BINS];      // per-column 9-bin partials (2016 f)

    if (t < ROWS * 8) {                    // zero left/right halo pads
        int r = t >> 3;
        int c = t & 7;
        int col = (c < 4) ? c : (224 + c);
        s[r][col] = 0.0f;
    }

    const int h0 = cr * 8 - 1;
    const float* xb = x + (size_t)n * 3 * Himg * Wimg;

    // Stage: 10 rows x 56 float4 chunks, summed over 3 channels.
    for (int idx = t; idx < ROWS * 56; idx += 256) {
        int r = idx / 56;
        int q = idx - r * 56;
        int w = q * 4;
        int h = h0 + r;
        float4 v = make_float4(0.f, 0.f, 0.f, 0.f);
        if (h >= 0 && h < Himg) {
            const float* r0 = xb + (size_t)h * Wimg;
            const float* r1 = r0 + Himg * Wimg;
            const float* r2 = r1 + Himg * Wimg;
            float4 a = *(const float4*)(r0 + w);
            float4 b = *(const float4*)(r1 + w);
            float4 c4 = *(const float4*)(r2 + w);
            v.x = a.x + b.x + c4.x;
            v.y = a.y + b.y + c4.y;
            v.z = a.z + b.z + c4.z;
            v.w = a.w + b.w + c4.w;
        }
        *(float4*)&s[r][4 + w] = v;
    }
    __syncthreads();

    const float PI_F = 3.14159265358979323846f;
    const float CK[8] = {0.92387953f, 0.70710678f, 0.38268343f, 0.0f,
                         -0.38268343f, -0.70710678f, -0.92387953f, -1.0f};

    if (t < Wimg) {
        const int w = t;                   // image column; lanes -> stride-1 LDS
        // 3x3 sliding window registers: rows (h-1,h,h+1) x cols (w-1,w,w+1)
        float ml = s[0][3 + w], mc = s[0][4 + w], mr = s[0][5 + w];  // row h-1
        float zl = s[1][3 + w], zc = s[1][4 + w], zr = s[1][5 + w];  // row h
        float acc[BINS];
#pragma unroll
        for (int j = 0; j < BINS; ++j) acc[j] = 0.0f;

#pragma unroll
        for (int i = 0; i < 8; ++i) {
            float pl = s[i + 2][3 + w];    // row h+1 (new row, 3 stride-1 reads)
            float pc = s[i + 2][4 + w];
            float pr = s[i + 2][5 + w];

            float gx = (mr - ml) + 2.0f * (zr - zl) + (pr - pl);
            float gy = (pl + 2.0f * pc + pr) - (ml + 2.0f * mc + mr);
            float mag = sqrtf(gx * gx + gy * gy);

            // bin = #{ j : gy <= mag*cos(j*pi/8) }
            float negy = -gy;
            int bin = 0;
            float guard = 1e30f;
#pragma unroll
            for (int j = 0; j < 8; ++j) {
                float sj = fmaf(mag, CK[j], negy);
                bin += (sj >= 0.0f) ? 1 : 0;
                guard = fminf(guard, fabsf(sj));
            }
            if (guard < mag * 1e-4f) {     // rare: exact reference pipeline
                float ang = fabsf(atan2f(gx, gy));
                bin = (int)(ang / PI_F * 8.0f);
                bin = bin > 8 ? 8 : bin;
            }
#pragma unroll
            for (int j = 0; j < BINS; ++j) acc[j] += (bin == j) ? mag : 0.0f;

            ml = zl; mc = zc; mr = zr;     // slide window down one row
            zl = pl; zc = pc; zr = pr;
        }
        // h2 addr = w*9+j: lanes stride 9, gcd(9,32)=1 -> conflict-free
#pragma unroll
        for (int j = 0; j < BINS; ++j) h2[w * BINS + j] = acc[j];
    }
    __syncthreads();

    // Reduce 8 columns per cell and write out[n, bin, cr, cw].
    if (t < NCELL * BINS) {
        int bin = t / NCELL;
        int cw  = t - bin * NCELL;
        float v = 0.0f;
#pragma unroll
        for (int c = 0; c < 8; ++c) v += h2[(cw * 8 + c) * BINS + bin];
        out[((size_t)n * BINS + bin) * (NCELL * NCELL) + (size_t)cr * NCELL + cw] = v;
    }
}
}  // namespace

extern "C" void kernel_launch(void* const* d_in, const int* in_sizes, int n_in,
                              void* d_out, int out_size, void* d_ws, size_t ws_size,
                              hipStream_t stream) {
    const float* x = (const float*)d_in[0];
    float* out = (float*)d_out;
    const int N = in_sizes[0] / (3 * Himg * Wimg);
    dim3 grid(NCELL, N);
    hog_kernel<<<grid, 256, 0, stream>>>(x, out);
}

// Round 4
// 83.492 us; speedup vs baseline: 1.1319x; 1.0041x over previous
//
#include <hip/hip_runtime.h>
#include <math.h>

// HOG: x (N,3,224,224) f32 -> out (N, 9*28*28) f32
// gx = sobelX(sum_c x), gy = sobelY(sum_c x)   [SAME zero pad]
// mag = sqrt(gx^2+gy^2); bin = floor(|atan2(gx,gy)|/pi*8) in [0,8]
// Bin via comparison network (gy <= mag*cos(k*pi/8)), guarded atan2f fallback
// within 1e-4*mag of any boundary -> binning provably matches the reference.
// R4 structure: 2 cell rows per block (512 thr, 896 blocks): staging is two
// fully-unrolled predicated float4 iterations (all 6 loads in flight before
// one waitcnt), halo overfetch 18/16, compute on 448 threads (whole waves),
// register sliding window + per-thread 9-bin acc, LDS column reduction.

namespace {
constexpr int Himg = 224;
constexpr int Wimg = 224;
constexpr int NCELL = 28;   // 224/8
constexpr int BINS  = 9;
constexpr int ROWS  = 18;   // 16 image rows + halo above/below
constexpr int LDSW  = 232;  // 4 left pad + 224 + 4 right pad (16B-aligned stores)
constexpr int NCHUNK = ROWS * 56;  // 1008 float4 chunks per tile

__global__ __launch_bounds__(512) void hog_kernel(const float* __restrict__ x,
                                                  float* __restrict__ out) {
    const int n  = blockIdx.y;   // sample
    const int pr = blockIdx.x;   // cell-row pair 0..13
    const int t  = threadIdx.x;  // 0..511

    __shared__ float s[ROWS][LDSW];        // channel-sum tile, col index = w + 4
    __shared__ float h2[448 * BINS];       // per-(column,cellrow) 9-bin partials

    if (t < ROWS * 8) {                    // zero left/right halo pads
        int r = t >> 3;
        int c = t & 7;
        int col = (c < 4) ? c : (224 + c);
        s[r][col] = 0.0f;
    }

    const int h0 = pr * 16 - 1;            // image row of LDS row 0
    const float* xb = x + (size_t)n * 3 * Himg * Wimg;

    // Stage: 1008 float4 chunks over 512 threads, exactly 2 unrolled iters.
    float4 va[2];
    int    lofs[2];
    bool   act[2];
#pragma unroll
    for (int k = 0; k < 2; ++k) {
        int idx = t + 512 * k;
        bool pred = idx < NCHUNK;
        int r = pred ? (idx / 56) : 0;
        int q = idx - r * 56;
        int w = q * 4;
        int h = h0 + r;
        act[k]  = pred;
        lofs[k] = r * LDSW + 4 + w;        // flat LDS float offset
        float4 v = make_float4(0.f, 0.f, 0.f, 0.f);
        if (pred && h >= 0 && h < Himg) {
            const float* r0 = xb + (size_t)h * Wimg + w;
            float4 a = *(const float4*)(r0);
            float4 b = *(const float4*)(r0 + Himg * Wimg);
            float4 c4 = *(const float4*)(r0 + 2 * Himg * Wimg);
            v.x = a.x + b.x + c4.x;
            v.y = a.y + b.y + c4.y;
            v.z = a.z + b.z + c4.z;
            v.w = a.w + b.w + c4.w;
        }
        va[k] = v;
    }
#pragma unroll
    for (int k = 0; k < 2; ++k)
        if (act[k]) *(float4*)&((float*)s)[lofs[k]] = va[k];
    __syncthreads();

    const float PI_F = 3.14159265358979323846f;
    const float CK[8] = {0.92387953f, 0.70710678f, 0.38268343f, 0.0f,
                         -0.38268343f, -0.70710678f, -0.92387953f, -1.0f};

    if (t < 448) {
        const int g = t >> 5 >= 7 ? 1 : 0;         // placeholder, fixed below
        const int gg = t / 224;                    // cell-row-within-pair 0/1
        const int w  = t - gg * 224;               // image column
        (void)g;
        const int rb = gg * 8;                     // LDS row base for this group
        float ml = s[rb][3 + w], mc = s[rb][4 + w], mr = s[rb][5 + w];
        float zl = s[rb + 1][3 + w], zc = s[rb + 1][4 + w], zr = s[rb + 1][5 + w];
        float acc[BINS];
#pragma unroll
        for (int j = 0; j < BINS; ++j) acc[j] = 0.0f;

#pragma unroll
        for (int i = 0; i < 8; ++i) {
            float pl = s[rb + i + 2][3 + w];
            float pc = s[rb + i + 2][4 + w];
            float pr2 = s[rb + i + 2][5 + w];

            float gx = (mr - ml) + 2.0f * (zr - zl) + (pr2 - pl);
            float gy = (pl + 2.0f * pc + pr2) - (ml + 2.0f * mc + mr);
            float mag = sqrtf(gx * gx + gy * gy);

            float negy = -gy;
            int bin = 0;
            float guard = 1e30f;
#pragma unroll
            for (int j = 0; j < 8; ++j) {
                float sj = fmaf(mag, CK[j], negy);
                bin += (sj >= 0.0f) ? 1 : 0;
                guard = fminf(guard, fabsf(sj));
            }
            if (guard < mag * 1e-4f) {     // rare: exact reference pipeline
                float ang = fabsf(atan2f(gx, gy));
                bin = (int)(ang / PI_F * 8.0f);
                bin = bin > 8 ? 8 : bin;
            }
#pragma unroll
            for (int j = 0; j < BINS; ++j) acc[j] += (bin == j) ? mag : 0.0f;

            ml = zl; mc = zc; mr = zr;
            zl = pl; zc = pc; zr = pr2;
        }
        // stride 9 (coprime with 32 banks) -> conflict-free
#pragma unroll
        for (int j = 0; j < BINS; ++j) h2[t * BINS + j] = acc[j];
    }
    __syncthreads();

    // Reduce 8 columns per cell; write out[n, bin, cr, cw] for 2 cell rows.
    if (t < 2 * NCELL * BINS) {            // 504 outputs
        int grp = t / (NCELL * BINS);
        int rem = t - grp * (NCELL * BINS);
        int bin = rem / NCELL;
        int cw  = rem - bin * NCELL;
        int cr  = pr * 2 + grp;
        float v = 0.0f;
#pragma unroll
        for (int c = 0; c < 8; ++c)
            v += h2[(grp * 224 + cw * 8 + c) * BINS + bin];
        out[((size_t)n * BINS + bin) * (NCELL * NCELL) + (size_t)cr * NCELL + cw] = v;
    }
}
}  // namespace

extern "C" void kernel_launch(void* const* d_in, const int* in_sizes, int n_in,
                              void* d_out, int out_size, void* d_ws, size_t ws_size,
                              hipStream_t stream) {
    const float* x = (const float*)d_in[0];
    float* out = (float*)d_out;
    const int N = in_sizes[0] / (3 * Himg * Wimg);
    dim3 grid(NCELL / 2, N);
    hog_kernel<<<grid, 512, 0, stream>>>(x, out);
}